// Round 3
// baseline (196.360 us; speedup 1.0000x reference)
//
#include <hip/hip_runtime.h>
#include <hip/hip_bf16.h>

typedef __bf16 bf16x8 __attribute__((ext_vector_type(8)));
typedef float f32x4 __attribute__((ext_vector_type(4)));
typedef unsigned int u32x4 __attribute__((ext_vector_type(4)));

#define QSCALE 0.18033688011112042f  /* 0.125 * log2(e) */

__device__ __forceinline__ void gload16(const void* g, void* l) {
  __builtin_amdgcn_global_load_lds(
      (const __attribute__((address_space(1))) uint32_t*)g,
      (__attribute__((address_space(3))) uint32_t*)l, 16, 0, 0);
}

__device__ __forceinline__ unsigned bf16bits(float f) {
  union { __bf16 h; unsigned short u; } c; c.h = (__bf16)f; return c.u;
}

// raw v_exp_f32: D = 2^x. Exact semantics we need (|x| small); skips OCML fixup.
__device__ __forceinline__ float exp2_raw(float x) {
  float r;
  asm("v_exp_f32 %0, %1" : "=v"(r) : "v"(x));
  return r;
}

// packed f32x2 -> bf16x2 in one reg (lo = a, hi = b)
__device__ __forceinline__ unsigned cvt_pk_bf16(float a, float b) {
  unsigned r;
  asm("v_cvt_pk_bf16_f32 %0, %1, %2" : "=v"(r) : "v"(a), "v"(b));
  return r;
}

// gfx950 cross-lane half swaps
#define SWAPL32(a, b) asm("v_permlane32_swap_b32 %0, %1" : "+v"(a), "+v"(b))
#define SWAPL16(a, b) asm("v_permlane16_swap_b32 %0, %1" : "+v"(a), "+v"(b))

// ---------------------------------------------------------------- fused fp32 -> bf16 casts
__global__ __launch_bounds__(256) void cast_all(
    const float* __restrict__ x, const float* __restrict__ wq, const float* __restrict__ wk,
    const float* __restrict__ wv, const float* __restrict__ wo,
    __bf16* __restrict__ xbf, __bf16* __restrict__ wqb, __bf16* __restrict__ wkb,
    __bf16* __restrict__ wvb, __bf16* __restrict__ wob) {
  int b = blockIdx.x;
  const float* src;
  __bf16* dst;
  int i;
  if (b < 4096) {
    src = x; dst = xbf; i = b * 256 + threadIdx.x;
  } else {
    int s = (b - 4096) >> 9;
    i = ((b - 4096) & 511) * 256 + threadIdx.x;
    src = (s == 0) ? wq : (s == 1) ? wk : (s == 2) ? wv : wo;
    dst = (s == 0) ? wqb : (s == 1) ? wkb : (s == 2) ? wvb : wob;
  }
  const float4* p = (const float4*)src;
  float4 a = p[2 * i], c = p[2 * i + 1];
  bf16x8 v;
  v[0] = (__bf16)a.x; v[1] = (__bf16)a.y; v[2] = (__bf16)a.z; v[3] = (__bf16)a.w;
  v[4] = (__bf16)c.x; v[5] = (__bf16)c.y; v[6] = (__bf16)c.z; v[7] = (__bf16)c.w;
  ((bf16x8*)dst)[i] = v;
}

// ---------------------------------------------------------------- 256x256 8-phase QKV GEMM
// T2+T3+T4+T5 per the catalog. BM=BN=256, BK=64 (2 K-tiles/iter), 8 waves.
// LDS 128KB: bufA/bufB[2][256*64]. Half-tiles are quadrant-interleaved (A-half h =
// rows with (row>>6)&1==h; B-half h = rows with (row>>5)&1==h) so each phase fully
// retires one half-tile (frags held in regs) and stages one half-tile in its place.
// Counted vmcnt(6) at phases 4/8 only (3 half-tiles in flight; FIFO audited).
// Swizzle: read elem ^= (l16&7)<<3; inverse perm applied to per-lane GLOBAL src
// (gload_lds writes linear) -> conflict-free 8-lane groups.
__global__ __launch_bounds__(512, 1) void gemm_qkv(
    const __bf16* __restrict__ A,
    const __bf16* __restrict__ W0, const __bf16* __restrict__ W1, const __bf16* __restrict__ W2,
    const float* __restrict__ b0, const float* __restrict__ b1, const float* __restrict__ b2,
    __bf16* __restrict__ o0, __bf16* __restrict__ o1, __bf16* __restrict__ o2) {
  __shared__ __bf16 bufA[2][256 * 64];
  __shared__ __bf16 bufB[2][256 * 64];
  const int t = threadIdx.x;
  const int lane = t & 63, w = t >> 6;
  const int l16 = lane & 15, l4 = lane >> 4;
  const int wr = w >> 2, wc = w & 3;

  // bijective XCD swizzle over 384 blocks (48 per XCD)
  const int flat = blockIdx.x + 32 * blockIdx.y;
  const int sb = (flat & 7) * 48 + (flat >> 3);
  const int m0 = (sb & 31) * 256;
  const int nb = sb >> 5;                 // 0..11
  const int sel = nb >> 2;
  const int bn = (nb & 3) * 256;
  const __bf16* W    = (sel == 0) ? W0 : (sel == 1) ? W1 : W2;
  const float* bias  = (sel == 0) ? b0 : (sel == 1) ? b1 : b2;

  // staging constants (per-thread)
  const int exo = (((t & 7) ^ ((t >> 3) & 7)) * 8);  // swizzled source elem offset
  const int rA  = t >> 3;                            // A: row-in-64-block
  const int cB  = (t & 255) >> 3;                    // B: row-in-32-block
  const int bB  = t >> 8;                            // B: block base 0..1
  const int c7  = (t & 7) * 8;                       // linear LDS elem offset in row
  const int xf  = (l16 & 7) << 3;                    // frag-read elem xor

#define STAGE_A(bi, h, ke)                                                      \
  { _Pragma("unroll") for (int j_ = 0; j_ < 2; j_++) {                          \
      int row_ = j_ * 128 + (h) * 64 + rA;                                      \
      gload16(A + (size_t)(m0 + row_) * 1024 + (ke) + exo,                      \
              &bufA[bi][row_ * 64 + c7]); } }
#define STAGE_B(bi, h, ke)                                                      \
  { _Pragma("unroll") for (int j_ = 0; j_ < 2; j_++) {                          \
      int row_ = (bB + 2 * j_) * 64 + (h) * 32 + cB;                            \
      gload16(W + (size_t)(bn + row_) * 1024 + (ke) + exo,                      \
              &bufB[bi][row_ * 64 + c7]); } }
#define LOADA(bi, qm)                                                           \
  _Pragma("unroll") for (int mm = 0; mm < 4; mm++)                              \
    _Pragma("unroll") for (int kk = 0; kk < 2; kk++)                            \
      a[mm][kk] = *(const bf16x8*)(&bufA[bi][(wr * 128 + (qm) * 64 + mm * 16 + l16) * 64 + ((kk * 32 + l4 * 8) ^ xf)]);
#define LOADB(bi, qn, B_)                                                       \
  _Pragma("unroll") for (int nn = 0; nn < 2; nn++)                              \
    _Pragma("unroll") for (int kk = 0; kk < 2; kk++)                            \
      B_[nn][kk] = *(const bf16x8*)(&bufB[bi][(wc * 64 + (qn) * 32 + nn * 16 + l16) * 64 + ((kk * 32 + l4 * 8) ^ xf)]);
#define MFMA_Q(qm, qn, B_)                                                      \
  { __builtin_amdgcn_s_setprio(1);                                              \
    _Pragma("unroll") for (int mm = 0; mm < 4; mm++)                            \
      _Pragma("unroll") for (int nn = 0; nn < 2; nn++)                          \
        _Pragma("unroll") for (int kk = 0; kk < 2; kk++)                        \
          acc[(qm) * 4 + mm][(qn) * 2 + nn] = __builtin_amdgcn_mfma_f32_16x16x32_bf16( \
              a[mm][kk], B_[nn][kk], acc[(qm) * 4 + mm][(qn) * 2 + nn], 0, 0, 0); \
    __builtin_amdgcn_s_setprio(0); }
#define BAR __builtin_amdgcn_s_barrier()
#define WAIT_LGKM { asm volatile("s_waitcnt lgkmcnt(0)" ::: "memory"); __builtin_amdgcn_sched_barrier(0); }
#define WAIT_VM(n) { asm volatile("s_waitcnt vmcnt(" #n ")" ::: "memory"); }

  f32x4 acc[8][4] = {};
  bf16x8 a[4][2], bq0[2][2], bq1[2][2];

  // prologue: Kt0 (4 halves) + Kt1 (3 halves); 8th half (Kt1 A-h1) staged at iter0 ph1
  STAGE_A(0, 0, 0);
  STAGE_B(0, 0, 0);
  STAGE_B(0, 1, 0);
  STAGE_A(0, 1, 0);
  STAGE_A(1, 0, 64);
  STAGE_B(1, 0, 64);
  STAGE_B(1, 1, 64);
  WAIT_VM(6);
  BAR;

#define ITER(i, LASTF)                                                          \
  {                                                                             \
    const int kO  = (2 * (i) + 1) * 64;                                         \
    const int kE2 = (2 * (i) + 2) * 64;                                         \
    const int kO2 = (2 * (i) + 3) * 64;                                         \
    /* ph1: quadrant (0,0) of Kt even (buf0) */                                 \
    LOADA(0, 0); LOADB(0, 0, bq0);                                              \
    STAGE_A(1, 1, kO);                                                          \
    BAR; WAIT_LGKM; MFMA_Q(0, 0, bq0); BAR;                                     \
    /* ph2: (0,1) */                                                            \
    LOADB(0, 1, bq1);                                                           \
    if (!(LASTF)) STAGE_A(0, 0, kE2);                                           \
    BAR; WAIT_LGKM; MFMA_Q(0, 1, bq1); BAR;                                     \
    /* ph3: (1,1) */                                                            \
    LOADA(0, 1);                                                                \
    if (!(LASTF)) STAGE_B(0, 0, kE2);                                           \
    BAR; WAIT_LGKM; MFMA_Q(1, 1, bq1); BAR;                                     \
    /* ph4: (1,0) + K-tile wait */                                              \
    if (!(LASTF)) STAGE_B(0, 1, kE2);                                           \
    BAR; WAIT_LGKM; MFMA_Q(1, 0, bq0);                                          \
    if (LASTF) { WAIT_VM(0); } else { WAIT_VM(6); }                             \
    BAR;                                                                        \
    /* ph5: (0,0) of Kt odd (buf1) */                                           \
    LOADA(1, 0); LOADB(1, 0, bq0);                                              \
    if (!(LASTF)) STAGE_A(0, 1, kE2);                                           \
    BAR; WAIT_LGKM; MFMA_Q(0, 0, bq0); BAR;                                     \
    /* ph6: (0,1) */                                                            \
    LOADB(1, 1, bq1);                                                           \
    if (!(LASTF)) STAGE_A(1, 0, kO2);                                           \
    BAR; WAIT_LGKM; MFMA_Q(0, 1, bq1); BAR;                                     \
    /* ph7: (1,1) */                                                            \
    LOADA(1, 1);                                                                \
    if (!(LASTF)) STAGE_B(1, 0, kO2);                                           \
    BAR; WAIT_LGKM; MFMA_Q(1, 1, bq1); BAR;                                     \
    /* ph8: (1,0) + K-tile wait */                                              \
    if (!(LASTF)) STAGE_B(1, 1, kO2);                                           \
    BAR; WAIT_LGKM; MFMA_Q(1, 0, bq0);                                          \
    if (!(LASTF)) { WAIT_VM(6); }                                               \
    BAR;                                                                        \
  }

  for (int i = 0; i < 7; ++i) ITER(i, 0);
  ITER(7, 1);
#undef ITER

  // epilogue: sel 0/1 -> [B,H,N,64] bf16 (Q scaled); sel 2 -> Vt [B,H,64,N]
#pragma unroll
  for (int ni = 0; ni < 4; ni++) {
    const int col = bn + wc * 64 + ni * 16 + l16;
    const float bv = bias[col];
    if (sel == 2) {
      const int h = col >> 6, hc = col & 63;
#pragma unroll
      for (int mi = 0; mi < 8; mi++) {
        const int nnb = m0 + wr * 128 + mi * 16 + l4 * 4;
        const int b_ = nnb >> 11, nn = nnb & 2047;
        ushort4 ov;
        ov.x = (unsigned short)bf16bits(acc[mi][ni][0] + bv);
        ov.y = (unsigned short)bf16bits(acc[mi][ni][1] + bv);
        ov.z = (unsigned short)bf16bits(acc[mi][ni][2] + bv);
        ov.w = (unsigned short)bf16bits(acc[mi][ni][3] + bv);
        *(ushort4*)(o2 + ((size_t)(b_ * 16 + h) * 64 + hc) * 2048 + nn) = ov;
      }
    } else {
      const float scl = (sel == 0) ? QSCALE : 1.0f;
      __bf16* outp = (sel == 0) ? o0 : o1;
      const int h = col >> 6, hc = col & 63;
#pragma unroll
      for (int mi = 0; mi < 8; mi++) {
#pragma unroll
        for (int j = 0; j < 4; j++) {
          const int row = m0 + wr * 128 + mi * 16 + l4 * 4 + j;
          float v = (acc[mi][ni][j] + bv) * scl;
          const int b_ = row >> 11, nn = row & 2047;
          outp[(((size_t)(b_ * 16 + h)) * 2048 + nn) * 64 + hc] = (__bf16)v;
        }
      }
    }
  }
#undef STAGE_A
#undef STAGE_B
#undef LOADA
#undef LOADB
#undef MFMA_Q
#undef BAR
#undef WAIT_LGKM
#undef WAIT_VM
}

// ---------------------------------------------------------------- NT GEMM (output proj)
// m97-pattern 128x128, BK=32. MODE 1: fp32 output with bias.
template <int MODE>
__global__ __launch_bounds__(256) void gemm_nt(
    const __bf16* __restrict__ A,
    const __bf16* __restrict__ W0, const __bf16* __restrict__ W1, const __bf16* __restrict__ W2,
    const float* __restrict__ b0, const float* __restrict__ b1, const float* __restrict__ b2,
    __bf16* __restrict__ o0, __bf16* __restrict__ o1, __bf16* __restrict__ o2,
    float* __restrict__ of) {
  __shared__ __bf16 lA[128 * 32];
  __shared__ __bf16 lB[128 * 32];
  const int t = threadIdx.x;
  const int lane = t & 63;
  const int w = t >> 6;
  const int wr = w >> 1, wc = w & 1;
  const int l16 = lane & 15, l4 = lane >> 4;
  const int m0 = blockIdx.x * 128;
  int sel, bn;
  if (MODE == 0) { sel = blockIdx.y >> 3; bn = (blockIdx.y & 7) * 128; }
  else           { sel = 0;               bn = blockIdx.y * 128; }
  const __bf16* W   = (sel == 0) ? W0 : (sel == 1) ? W1 : W2;
  const float* bias = (sel == 0) ? b0 : (sel == 1) ? b1 : b2;

  f32x4 acc[4][4] = {};

  for (int k0 = 0; k0 < 1024; k0 += 32) {
    __syncthreads();
#pragma unroll
    for (int i = 0; i < 2; i++) {
      int c = t + i * 256;
      int r = c >> 2, cp = c & 3;
      gload16(A + (size_t)(m0 + r) * 1024 + k0 + cp * 8, lA + c * 8);
      gload16(W + (size_t)(bn + r) * 1024 + k0 + cp * 8, lB + c * 8);
    }
    __syncthreads();
    bf16x8 af[4], bfr[4];
#pragma unroll
    for (int m = 0; m < 4; m++)
      af[m] = *(const bf16x8*)(lA + (wr * 64 + m * 16 + l16) * 32 + l4 * 8);
#pragma unroll
    for (int n = 0; n < 4; n++)
      bfr[n] = *(const bf16x8*)(lB + (wc * 64 + n * 16 + l16) * 32 + l4 * 8);
#pragma unroll
    for (int m = 0; m < 4; m++)
#pragma unroll
      for (int n = 0; n < 4; n++)
        acc[m][n] = __builtin_amdgcn_mfma_f32_16x16x32_bf16(af[m], bfr[n], acc[m][n], 0, 0, 0);
  }

  const float scl = (MODE == 0 && sel == 0) ? QSCALE : 1.0f;
  __bf16* outp = (sel == 0) ? o0 : (sel == 1) ? o1 : o2;
#pragma unroll
  for (int n = 0; n < 4; n++) {
    const int col = bn + wc * 64 + n * 16 + l16;
    const float bv = bias[col];
    if (MODE == 0 && sel == 2) {
      const int h = col >> 6, hc = col & 63;
#pragma unroll
      for (int m = 0; m < 4; m++) {
        const int nnb = m0 + wr * 64 + m * 16 + l4 * 4;
        const int b_ = nnb >> 11, nn = nnb & 2047;
        ushort4 ov;
        ov.x = (unsigned short)bf16bits(acc[m][n][0] + bv);
        ov.y = (unsigned short)bf16bits(acc[m][n][1] + bv);
        ov.z = (unsigned short)bf16bits(acc[m][n][2] + bv);
        ov.w = (unsigned short)bf16bits(acc[m][n][3] + bv);
        *(ushort4*)(outp + ((size_t)(b_ * 16 + h) * 64 + hc) * 2048 + nn) = ov;
      }
    } else {
#pragma unroll
      for (int m = 0; m < 4; m++) {
#pragma unroll
        for (int j = 0; j < 4; j++) {
          const int row = m0 + wr * 64 + m * 16 + l4 * 4 + j;
          float v = acc[m][n][j] + bv;
          if (MODE == 0) {
            v *= scl;
            int b_ = row >> 11, nn = row & 2047;
            int h = col >> 6, hc = col & 63;
            outp[(((size_t)(b_ * 16 + h)) * 2048 + nn) * 64 + hc] = (__bf16)v;
          } else {
            of[(size_t)row * 1024 + col] = v;
          }
        }
      }
    }
  }
}

// ---------------------------------------------------------------- flash attention
// R15 structure (unchanged this round): QK(t+1) MFMA interleaved with softmax(t)
// VALU; full-rate K=32 PV; MFMA row-sums; double-buffered gload16 staging.
__global__ __launch_bounds__(256) void attn_fwd(const __bf16* __restrict__ Q,
                                                const __bf16* __restrict__ K,
                                                const __bf16* __restrict__ Vt,
                                                __bf16* __restrict__ O) {
  __shared__ __bf16 sm[16384];
  const int flat = blockIdx.x;
  const int wg = (flat & 7) * 128 + (flat >> 3);
  const int bh = wg >> 4;
  const int q0 = (wg & 15) * 128;
  const __bf16* Qh = Q + (size_t)bh * 2048 * 64;
  const __bf16* Kh = K + (size_t)bh * 2048 * 64;
  const __bf16* Vh = Vt + (size_t)bh * 64 * 2048;
  const int t = threadIdx.x, lane = t & 63, w = t >> 6;
  const int l16 = lane & 15, l4 = lane >> 4;

  bf16x8 qf[2][2];
#pragma unroll
  for (int st = 0; st < 2; st++)
#pragma unroll
    for (int kk = 0; kk < 2; kk++)
      qf[st][kk] = *(const bf16x8*)(Qh + (size_t)(q0 + w * 32 + st * 16 + l16) * 64 + kk * 32 + l4 * 8);

  f32x4 ao[2][4] = {};
  f32x4 rs4[2] = {};
  bf16x8 onesf;
#pragma unroll
  for (int i = 0; i < 8; i++) onesf[i] = (__bf16)1.0f;

  const int rdbase = l4 * 512 + l16 * 8;
  const int vb = 8192 + l4 * 512 + l16 * 8;

  f32x4 sA[2][4], sB[2][4];

#pragma unroll
  for (int i = 0; i < 2; i++) {
    int ic = w * 2 + i;
    gload16(Kh + (size_t)lane * 64 + ic * 8,          sm + ic * 512 + lane * 8);
    gload16(Vh + (size_t)lane * 2048 + ic * 8,        sm + 8192 + ic * 512 + lane * 8);
    gload16(Kh + (size_t)(64 + lane) * 64 + ic * 8,   sm + 4096 + ic * 512 + lane * 8);
    gload16(Vh + (size_t)lane * 2048 + 64 + ic * 8,   sm + 12288 + ic * 512 + lane * 8);
  }
  __syncthreads();

#define QK_N(KLDS, SCUR, n)                                                    \
  {                                                                            \
    bf16x8 kf0 = *(const bf16x8*)((KLDS) + rdbase + (n) * 128);                \
    bf16x8 kf1 = *(const bf16x8*)((KLDS) + rdbase + 2048 + (n) * 128);         \
    f32x4 z = {};                                                              \
    SCUR[0][(n)] = __builtin_amdgcn_mfma_f32_16x16x32_bf16(kf0, qf[0][0], z, 0, 0, 0); \
    SCUR[1][(n)] = __builtin_amdgcn_mfma_f32_16x16x32_bf16(kf0, qf[1][0], z, 0, 0, 0); \
    SCUR[0][(n)] = __builtin_amdgcn_mfma_f32_16x16x32_bf16(kf1, qf[0][1], SCUR[0][(n)], 0, 0, 0); \
    SCUR[1][(n)] = __builtin_amdgcn_mfma_f32_16x16x32_bf16(kf1, qf[1][1], SCUR[1][(n)], 0, 0, 0); \
  }

#define SM_GROUP(SP, st_, g_)                                                  \
  {                                                                            \
    float p0 = exp2_raw(SP[(st_)][2 * (g_)][0]),     p1 = exp2_raw(SP[(st_)][2 * (g_)][1]); \
    float p2 = exp2_raw(SP[(st_)][2 * (g_)][2]),     p3 = exp2_raw(SP[(st_)][2 * (g_)][3]); \
    float p4 = exp2_raw(SP[(st_)][2 * (g_) + 1][0]), p5 = exp2_raw(SP[(st_)][2 * (g_) + 1][1]); \
    float p6 = exp2_raw(SP[(st_)][2 * (g_) + 1][2]), p7 = exp2_raw(SP[(st_)][2 * (g_) + 1][3]); \
    unsigned c00 = cvt_pk_bf16(p0, p1), c01 = cvt_pk_bf16(p2, p3);             \
    unsigned c10 = cvt_pk_bf16(p4, p5), c11 = cvt_pk_bf16(p6, p7);             \
    SWAPL32(c00, c10); SWAPL32(c01, c11);                                      \
    SWAPL16(c00, c10); SWAPL16(c01, c11);                                      \
    u32x4 tv = {c00, c01, c10, c11};                                           \
    pk[(st_)][(g_)] = tv;                                                      \
  }

#define ATTN_ITER(T, CUR, SPREV, SCUR)                                         \
  {                                                                            \
    const __bf16* vlds = sm + (CUR) * 4096;                                    \
    bf16x8 vf[2][4];                                                           \
    _Pragma("unroll")                                                          \
    for (int g = 0; g < 2; g++)                                                \
      _Pragma("unroll")                                                        \
      for (int cb = 0; cb < 4; cb++)                                           \
        vf[g][cb] = *(const bf16x8*)(vlds + vb + g * 2048 + cb * 128);         \
    __syncthreads();                                                           \
    if ((T) + 2 < 32) {                                                        \
      const int kvn = ((T) + 2) * 64;                                          \
      __bf16* dst = sm + (CUR) * 4096;                                         \
      _Pragma("unroll")                                                        \
      for (int i = 0; i < 2; i++) {                                            \
        int ic = w * 2 + i;                                                    \
        gload16(Kh + (size_t)(kvn + lane) * 64 + ic * 8, dst + ic * 512 + lane * 8); \
        gload16(Vh + (size_t)lane * 2048 + kvn + ic * 8, dst + 8192 + ic * 512 + lane * 8); \
      }                                                                        \
    }                                                                          \
    u32x4 pk[2][2];                                                            \
    __builtin_amdgcn_s_setprio(1);                                             \
    if ((T) + 1 < 32) {                                                        \
      const __bf16* klds = sm + ((CUR) ^ 1) * 4096;                            \
      _Pragma("unroll")                                                        \
      for (int n = 0; n < 4; n++) {                                            \
        QK_N(klds, SCUR, n);                                                   \
        SM_GROUP(SPREV, (n >> 1), (n & 1));                                    \
      }                                                                        \
    } else {                                                                   \
      _Pragma("unroll")                                                        \
      for (int n = 0; n < 4; n++) SM_GROUP(SPREV, (n >> 1), (n & 1));          \
    }                                                                          \
    _Pragma("unroll")                                                          \
    for (int st = 0; st < 2; st++)                                             \
      _Pragma("unroll")                                                        \
      for (int g = 0; g < 2; g++) {                                            \
        union { u32x4 u; bf16x8 h; } cv; cv.u = pk[st][g];                     \
        rs4[st] = __builtin_amdgcn_mfma_f32_16x16x32_bf16(onesf, cv.h, rs4[st], 0, 0, 0); \
        _Pragma("unroll")                                                      \
        for (int cb = 0; cb < 4; cb++)                                         \
          ao[st][cb] = __builtin_amdgcn_mfma_f32_16x16x32_bf16(vf[g][cb], cv.h, ao[st][cb], 0, 0, 0); \
      }                                                                        \
    __builtin_amdgcn_s_setprio(0);                                             \
  }

#pragma unroll
  for (int n = 0; n < 4; n++) QK_N(sm, sA, n);

  for (int tkv = 0; tkv < 32; tkv += 2) {
    ATTN_ITER(tkv,     0, sA, sB);
    ATTN_ITER(tkv + 1, 1, sB, sA);
  }
#undef ATTN_ITER
#undef SM_GROUP
#undef QK_N

  const int b_ = bh >> 4, h = bh & 15;
#pragma unroll
  for (int st = 0; st < 2; st++) {
    const float inv = 1.f / rs4[st][0];
    const int qrow = q0 + w * 32 + st * 16 + l16;
#pragma unroll
    for (int cb = 0; cb < 4; cb++) {
      ushort4 ov;
      ov.x = (unsigned short)bf16bits(ao[st][cb][0] * inv);
      ov.y = (unsigned short)bf16bits(ao[st][cb][1] * inv);
      ov.z = (unsigned short)bf16bits(ao[st][cb][2] * inv);
      ov.w = (unsigned short)bf16bits(ao[st][cb][3] * inv);
      *(ushort4*)(O + ((size_t)b_ * 2048 + qrow) * 1024 + h * 64 + cb * 16 + l4 * 4) = ov;
    }
  }
}

// ---------------------------------------------------------------- launch
extern "C" void kernel_launch(void* const* d_in, const int* in_sizes, int n_in,
                              void* d_out, int out_size, void* d_ws, size_t ws_size,
                              hipStream_t stream) {
  const float* x  = (const float*)d_in[0];
  const float* wq = (const float*)d_in[1];
  const float* bq = (const float*)d_in[2];
  const float* wk = (const float*)d_in[3];
  const float* bk = (const float*)d_in[4];
  const float* wv = (const float*)d_in[5];
  const float* bv = (const float*)d_in[6];
  const float* wo = (const float*)d_in[7];
  const float* bo = (const float*)d_in[8];
  float* out = (float*)d_out;

  const size_t NX = 8388608;   // 8192*1024
  const size_t NW = 1048576;   // 1024*1024
  __bf16* xbf = (__bf16*)d_ws;       // also reused as attention output O
  __bf16* wqb = xbf + NX;
  __bf16* wkb = wqb + NW;
  __bf16* wvb = wkb + NW;
  __bf16* wob = wvb + NW;
  __bf16* Qb  = wob + NW;
  __bf16* Kb  = Qb + NX;
  __bf16* Vtb = Kb + NX;

  cast_all<<<6144, 256, 0, stream>>>(x, wq, wk, wv, wo, xbf, wqb, wkb, wvb, wob);

  gemm_qkv<<<dim3(32, 12), 512, 0, stream>>>(xbf, wqb, wkb, wvb, bq, bk, bv,
                                             Qb, Kb, Vtb);
  attn_fwd<<<1024, 256, 0, stream>>>(Qb, Kb, Vtb, xbf /* O */);
  gemm_nt<1><<<dim3(64, 8), 256, 0, stream>>>(xbf, wob, nullptr, nullptr, bo, nullptr, nullptr,
                                              nullptr, nullptr, nullptr, out);
}

// Round 4
// 193.135 us; speedup vs baseline: 1.0167x; 1.0167x over previous
//
#include <hip/hip_runtime.h>
#include <hip/hip_bf16.h>

typedef __bf16 bf16x8 __attribute__((ext_vector_type(8)));
typedef float f32x4 __attribute__((ext_vector_type(4)));
typedef unsigned int u32x4 __attribute__((ext_vector_type(4)));

#define QSCALE 0.18033688011112042f  /* 0.125 * log2(e) */

__device__ __forceinline__ void gload16(const void* g, void* l) {
  __builtin_amdgcn_global_load_lds(
      (const __attribute__((address_space(1))) uint32_t*)g,
      (__attribute__((address_space(3))) uint32_t*)l, 16, 0, 0);
}

__device__ __forceinline__ unsigned bf16bits(float f) {
  union { __bf16 h; unsigned short u; } c; c.h = (__bf16)f; return c.u;
}

// raw v_exp_f32: D = 2^x. Exact semantics we need (|x| small); skips OCML fixup.
__device__ __forceinline__ float exp2_raw(float x) {
  float r;
  asm("v_exp_f32 %0, %1" : "=v"(r) : "v"(x));
  return r;
}

// packed f32x2 -> bf16x2 in one reg (lo = a, hi = b)
__device__ __forceinline__ unsigned cvt_pk_bf16(float a, float b) {
  unsigned r;
  asm("v_cvt_pk_bf16_f32 %0, %1, %2" : "=v"(r) : "v"(a), "v"(b));
  return r;
}

// gfx950 cross-lane half swaps
#define SWAPL32(a, b) asm("v_permlane32_swap_b32 %0, %1" : "+v"(a), "+v"(b))
#define SWAPL16(a, b) asm("v_permlane16_swap_b32 %0, %1" : "+v"(a), "+v"(b))

// ---------------------------------------------------------------- fused fp32 -> bf16 casts
__global__ __launch_bounds__(256) void cast_all(
    const float* __restrict__ x, const float* __restrict__ wq, const float* __restrict__ wk,
    const float* __restrict__ wv, const float* __restrict__ wo,
    __bf16* __restrict__ xbf, __bf16* __restrict__ wqb, __bf16* __restrict__ wkb,
    __bf16* __restrict__ wvb, __bf16* __restrict__ wob) {
  int b = blockIdx.x;
  const float* src;
  __bf16* dst;
  int i;
  if (b < 4096) {
    src = x; dst = xbf; i = b * 256 + threadIdx.x;
  } else {
    int s = (b - 4096) >> 9;
    i = ((b - 4096) & 511) * 256 + threadIdx.x;
    src = (s == 0) ? wq : (s == 1) ? wk : (s == 2) ? wv : wo;
    dst = (s == 0) ? wqb : (s == 1) ? wkb : (s == 2) ? wvb : wob;
  }
  const float4* p = (const float4*)src;
  float4 a = p[2 * i], c = p[2 * i + 1];
  bf16x8 v;
  v[0] = (__bf16)a.x; v[1] = (__bf16)a.y; v[2] = (__bf16)a.z; v[3] = (__bf16)a.w;
  v[4] = (__bf16)c.x; v[5] = (__bf16)c.y; v[6] = (__bf16)c.z; v[7] = (__bf16)c.w;
  ((bf16x8*)dst)[i] = v;
}

// ---------------------------------------------------------------- 256x256 8-phase QKV GEMM
// R16: un-pin the schedule. vs R15's port: (1) NO asm lgkmcnt / NO sched_barrier —
// the ds_reads are compiler-visible, so the backend emits fine-grained
// lgkmcnt(4/3/1/0) and starts MFMAs as soon as their frags land (m97 evidence;
// R15's pin was the m141 failure mode). (2) ONE barrier per phase (closing only;
// raw s_barrier + zero-cost compiler fences). WAR audit: a slot staged at phase
// p+1 was last ds_read at phase p, and every reader's ds_read completes before
// its own MFMA (hw lgkm) which precedes the closing barrier -> write-after-read
// safe with a single barrier. RAW: fresh stages are only consumed after a
// vmcnt(6)-bearing phase's barrier (FIFO audit: at ph4 outstanding = prev ph6,7,8
// + ph1..4 = 7 stages = 14 instr; vmcnt(6) completes 8 oldest = exactly the 4
// halves needed for ph5-8; symmetric at ph8). Counted vmcnt never 0 mid-loop.
__global__ __launch_bounds__(512, 1) void gemm_qkv(
    const __bf16* __restrict__ A,
    const __bf16* __restrict__ W0, const __bf16* __restrict__ W1, const __bf16* __restrict__ W2,
    const float* __restrict__ b0, const float* __restrict__ b1, const float* __restrict__ b2,
    __bf16* __restrict__ o0, __bf16* __restrict__ o1, __bf16* __restrict__ o2) {
  __shared__ __bf16 bufA[2][256 * 64];
  __shared__ __bf16 bufB[2][256 * 64];
  const int t = threadIdx.x;
  const int lane = t & 63, w = t >> 6;
  const int l16 = lane & 15, l4 = lane >> 4;
  const int wr = w >> 2, wc = w & 3;

  // bijective XCD swizzle over 384 blocks (48 per XCD)
  const int flat = blockIdx.x + 32 * blockIdx.y;
  const int sb = (flat & 7) * 48 + (flat >> 3);
  const int m0 = (sb & 31) * 256;
  const int nb = sb >> 5;                 // 0..11
  const int sel = nb >> 2;
  const int bn = (nb & 3) * 256;
  const __bf16* W    = (sel == 0) ? W0 : (sel == 1) ? W1 : W2;
  const float* bias  = (sel == 0) ? b0 : (sel == 1) ? b1 : b2;

  // staging constants (per-thread). LDS dest is linear in lane order (gload_lds
  // writes base+lane*16); swizzle is applied to the GLOBAL source (involution),
  // and the same XOR on the frag-read side.
  const int exo = (((t & 7) ^ ((t >> 3) & 7)) * 8);  // swizzled source elem offset
  const int rA  = t >> 3;                            // A: row-in-64-block
  const int cB  = (t & 255) >> 3;                    // B: row-in-32-block
  const int bB  = t >> 8;                            // B: block base 0..1
  const int c7  = (t & 7) * 8;                       // linear LDS elem offset in row
  const int xf  = (l16 & 7) << 3;                    // frag-read elem xor

#define STAGE_A(bi, h, ke)                                                      \
  { _Pragma("unroll") for (int j_ = 0; j_ < 2; j_++) {                          \
      int row_ = j_ * 128 + (h) * 64 + rA;                                      \
      gload16(A + (size_t)(m0 + row_) * 1024 + (ke) + exo,                      \
              &bufA[bi][row_ * 64 + c7]); } }
#define STAGE_B(bi, h, ke)                                                      \
  { _Pragma("unroll") for (int j_ = 0; j_ < 2; j_++) {                          \
      int row_ = (bB + 2 * j_) * 64 + (h) * 32 + cB;                            \
      gload16(W + (size_t)(bn + row_) * 1024 + (ke) + exo,                      \
              &bufB[bi][row_ * 64 + c7]); } }
#define LOADA(bi, qm)                                                           \
  _Pragma("unroll") for (int mm = 0; mm < 4; mm++)                              \
    _Pragma("unroll") for (int kk = 0; kk < 2; kk++)                            \
      a[mm][kk] = *(const bf16x8*)(&bufA[bi][(wr * 128 + (qm) * 64 + mm * 16 + l16) * 64 + ((kk * 32 + l4 * 8) ^ xf)]);
#define LOADB(bi, qn, B_)                                                       \
  _Pragma("unroll") for (int nn = 0; nn < 2; nn++)                              \
    _Pragma("unroll") for (int kk = 0; kk < 2; kk++)                            \
      B_[nn][kk] = *(const bf16x8*)(&bufB[bi][(wc * 64 + (qn) * 32 + nn * 16 + l16) * 64 + ((kk * 32 + l4 * 8) ^ xf)]);
#define MFMA_Q(qm, qn, B_)                                                      \
  { __builtin_amdgcn_s_setprio(1);                                              \
    _Pragma("unroll") for (int mm = 0; mm < 4; mm++)                            \
      _Pragma("unroll") for (int nn = 0; nn < 2; nn++)                          \
        _Pragma("unroll") for (int kk = 0; kk < 2; kk++)                        \
          acc[(qm) * 4 + mm][(qn) * 2 + nn] = __builtin_amdgcn_mfma_f32_16x16x32_bf16( \
              a[mm][kk], B_[nn][kk], acc[(qm) * 4 + mm][(qn) * 2 + nn], 0, 0, 0); \
    __builtin_amdgcn_s_setprio(0); }
#define BARX { asm volatile("" ::: "memory"); __builtin_amdgcn_s_barrier(); asm volatile("" ::: "memory"); }
#define WAIT_VM(n) asm volatile("s_waitcnt vmcnt(" #n ")" ::: "memory")

  f32x4 acc[8][4] = {};
  bf16x8 a[4][2], bq0[2][2], bq1[2][2];

  // prologue: Kt0 (4 halves) + Kt1 (3 halves); 8th half (Kt1 A-h1) staged at iter0 ph1
  STAGE_A(0, 0, 0);
  STAGE_B(0, 0, 0);
  STAGE_B(0, 1, 0);
  STAGE_A(0, 1, 0);
  STAGE_A(1, 0, 64);
  STAGE_B(1, 0, 64);
  STAGE_B(1, 1, 64);
  WAIT_VM(6);   // 14 instr outstanding -> 8 oldest (all of buf0) complete
  BARX;

#define ITER(i, LASTF)                                                          \
  {                                                                             \
    const int kO  = (2 * (i) + 1) * 64;                                         \
    const int kE2 = (2 * (i) + 2) * 64;                                         \
    const int kO2 = (2 * (i) + 3) * 64;                                         \
    /* ph1: quadrant (0,0) of Kt even (buf0) */                                 \
    LOADA(0, 0); LOADB(0, 0, bq0);                                              \
    STAGE_A(1, 1, kO);                                                          \
    MFMA_Q(0, 0, bq0); BARX;                                                    \
    /* ph2: (0,1) */                                                            \
    LOADB(0, 1, bq1);                                                           \
    if (!(LASTF)) STAGE_A(0, 0, kE2);                                           \
    MFMA_Q(0, 1, bq1); BARX;                                                    \
    /* ph3: (1,1) */                                                            \
    LOADA(0, 1);                                                                \
    if (!(LASTF)) STAGE_B(0, 0, kE2);                                           \
    MFMA_Q(1, 1, bq1); BARX;                                                    \
    /* ph4: (1,0) + K-tile wait */                                              \
    if (!(LASTF)) STAGE_B(0, 1, kE2);                                           \
    MFMA_Q(1, 0, bq0);                                                          \
    if (LASTF) { WAIT_VM(0); } else { WAIT_VM(6); }                             \
    BARX;                                                                       \
    /* ph5: (0,0) of Kt odd (buf1) */                                           \
    LOADA(1, 0); LOADB(1, 0, bq0);                                              \
    if (!(LASTF)) STAGE_A(0, 1, kE2);                                           \
    MFMA_Q(0, 0, bq0); BARX;                                                    \
    /* ph6: (0,1) */                                                            \
    LOADB(1, 1, bq1);                                                           \
    if (!(LASTF)) STAGE_A(1, 0, kO2);                                           \
    MFMA_Q(0, 1, bq1); BARX;                                                    \
    /* ph7: (1,1) */                                                            \
    LOADA(1, 1);                                                                \
    if (!(LASTF)) STAGE_B(1, 0, kO2);                                           \
    MFMA_Q(1, 1, bq1); BARX;                                                    \
    /* ph8: (1,0) + K-tile wait */                                              \
    if (!(LASTF)) STAGE_B(1, 1, kO2);                                           \
    MFMA_Q(1, 0, bq0);                                                          \
    if (!(LASTF)) { WAIT_VM(6); }                                               \
    BARX;                                                                       \
  }

  for (int i = 0; i < 7; ++i) ITER(i, 0);
  ITER(7, 1);
#undef ITER

  // epilogue: sel 0/1 -> [B,H,N,64] bf16 (Q scaled); sel 2 -> Vt [B,H,64,N]
#pragma unroll
  for (int ni = 0; ni < 4; ni++) {
    const int col = bn + wc * 64 + ni * 16 + l16;
    const float bv = bias[col];
    if (sel == 2) {
      const int h = col >> 6, hc = col & 63;
#pragma unroll
      for (int mi = 0; mi < 8; mi++) {
        const int nnb = m0 + wr * 128 + mi * 16 + l4 * 4;
        const int b_ = nnb >> 11, nn = nnb & 2047;
        ushort4 ov;
        ov.x = (unsigned short)bf16bits(acc[mi][ni][0] + bv);
        ov.y = (unsigned short)bf16bits(acc[mi][ni][1] + bv);
        ov.z = (unsigned short)bf16bits(acc[mi][ni][2] + bv);
        ov.w = (unsigned short)bf16bits(acc[mi][ni][3] + bv);
        *(ushort4*)(o2 + ((size_t)(b_ * 16 + h) * 64 + hc) * 2048 + nn) = ov;
      }
    } else {
      const float scl = (sel == 0) ? QSCALE : 1.0f;
      __bf16* outp = (sel == 0) ? o0 : o1;
      const int h = col >> 6, hc = col & 63;
#pragma unroll
      for (int mi = 0; mi < 8; mi++) {
#pragma unroll
        for (int j = 0; j < 4; j++) {
          const int row = m0 + wr * 128 + mi * 16 + l4 * 4 + j;
          float v = (acc[mi][ni][j] + bv) * scl;
          const int b_ = row >> 11, nn = row & 2047;
          outp[(((size_t)(b_ * 16 + h)) * 2048 + nn) * 64 + hc] = (__bf16)v;
        }
      }
    }
  }
#undef STAGE_A
#undef STAGE_B
#undef LOADA
#undef LOADB
#undef MFMA_Q
#undef BARX
#undef WAIT_VM
}

// ---------------------------------------------------------------- NT GEMM (output proj)
// m97-pattern 128x128, BK=32. MODE 1: fp32 output with bias.
template <int MODE>
__global__ __launch_bounds__(256) void gemm_nt(
    const __bf16* __restrict__ A,
    const __bf16* __restrict__ W0, const __bf16* __restrict__ W1, const __bf16* __restrict__ W2,
    const float* __restrict__ b0, const float* __restrict__ b1, const float* __restrict__ b2,
    __bf16* __restrict__ o0, __bf16* __restrict__ o1, __bf16* __restrict__ o2,
    float* __restrict__ of) {
  __shared__ __bf16 lA[128 * 32];
  __shared__ __bf16 lB[128 * 32];
  const int t = threadIdx.x;
  const int lane = t & 63;
  const int w = t >> 6;
  const int wr = w >> 1, wc = w & 1;
  const int l16 = lane & 15, l4 = lane >> 4;
  const int m0 = blockIdx.x * 128;
  int sel, bn;
  if (MODE == 0) { sel = blockIdx.y >> 3; bn = (blockIdx.y & 7) * 128; }
  else           { sel = 0;               bn = blockIdx.y * 128; }
  const __bf16* W   = (sel == 0) ? W0 : (sel == 1) ? W1 : W2;
  const float* bias = (sel == 0) ? b0 : (sel == 1) ? b1 : b2;

  f32x4 acc[4][4] = {};

  for (int k0 = 0; k0 < 1024; k0 += 32) {
    __syncthreads();
#pragma unroll
    for (int i = 0; i < 2; i++) {
      int c = t + i * 256;
      int r = c >> 2, cp = c & 3;
      gload16(A + (size_t)(m0 + r) * 1024 + k0 + cp * 8, lA + c * 8);
      gload16(W + (size_t)(bn + r) * 1024 + k0 + cp * 8, lB + c * 8);
    }
    __syncthreads();
    bf16x8 af[4], bfr[4];
#pragma unroll
    for (int m = 0; m < 4; m++)
      af[m] = *(const bf16x8*)(lA + (wr * 64 + m * 16 + l16) * 32 + l4 * 8);
#pragma unroll
    for (int n = 0; n < 4; n++)
      bfr[n] = *(const bf16x8*)(lB + (wc * 64 + n * 16 + l16) * 32 + l4 * 8);
#pragma unroll
    for (int m = 0; m < 4; m++)
#pragma unroll
      for (int n = 0; n < 4; n++)
        acc[m][n] = __builtin_amdgcn_mfma_f32_16x16x32_bf16(af[m], bfr[n], acc[m][n], 0, 0, 0);
  }

  const float scl = (MODE == 0 && sel == 0) ? QSCALE : 1.0f;
  __bf16* outp = (sel == 0) ? o0 : (sel == 1) ? o1 : o2;
#pragma unroll
  for (int n = 0; n < 4; n++) {
    const int col = bn + wc * 64 + n * 16 + l16;
    const float bv = bias[col];
    if (MODE == 0 && sel == 2) {
      const int h = col >> 6, hc = col & 63;
#pragma unroll
      for (int m = 0; m < 4; m++) {
        const int nnb = m0 + wr * 64 + m * 16 + l4 * 4;
        const int b_ = nnb >> 11, nn = nnb & 2047;
        ushort4 ov;
        ov.x = (unsigned short)bf16bits(acc[m][n][0] + bv);
        ov.y = (unsigned short)bf16bits(acc[m][n][1] + bv);
        ov.z = (unsigned short)bf16bits(acc[m][n][2] + bv);
        ov.w = (unsigned short)bf16bits(acc[m][n][3] + bv);
        *(ushort4*)(outp + ((size_t)(b_ * 16 + h) * 64 + hc) * 2048 + nn) = ov;
      }
    } else {
#pragma unroll
      for (int m = 0; m < 4; m++) {
#pragma unroll
        for (int j = 0; j < 4; j++) {
          const int row = m0 + wr * 64 + m * 16 + l4 * 4 + j;
          float v = acc[m][n][j] + bv;
          if (MODE == 0) {
            v *= scl;
            int b_ = row >> 11, nn = row & 2047;
            int h = col >> 6, hc = col & 63;
            outp[(((size_t)(b_ * 16 + h)) * 2048 + nn) * 64 + hc] = (__bf16)v;
          } else {
            of[(size_t)row * 1024 + col] = v;
          }
        }
      }
    }
  }
}

// ---------------------------------------------------------------- flash attention
// R15 structure (unchanged): QK(t+1) MFMA interleaved with softmax(t) VALU;
// full-rate K=32 PV; MFMA row-sums; double-buffered gload16 staging.
__global__ __launch_bounds__(256) void attn_fwd(const __bf16* __restrict__ Q,
                                                const __bf16* __restrict__ K,
                                                const __bf16* __restrict__ Vt,
                                                __bf16* __restrict__ O) {
  __shared__ __bf16 sm[16384];
  const int flat = blockIdx.x;
  const int wg = (flat & 7) * 128 + (flat >> 3);
  const int bh = wg >> 4;
  const int q0 = (wg & 15) * 128;
  const __bf16* Qh = Q + (size_t)bh * 2048 * 64;
  const __bf16* Kh = K + (size_t)bh * 2048 * 64;
  const __bf16* Vh = Vt + (size_t)bh * 64 * 2048;
  const int t = threadIdx.x, lane = t & 63, w = t >> 6;
  const int l16 = lane & 15, l4 = lane >> 4;

  bf16x8 qf[2][2];
#pragma unroll
  for (int st = 0; st < 2; st++)
#pragma unroll
    for (int kk = 0; kk < 2; kk++)
      qf[st][kk] = *(const bf16x8*)(Qh + (size_t)(q0 + w * 32 + st * 16 + l16) * 64 + kk * 32 + l4 * 8);

  f32x4 ao[2][4] = {};
  f32x4 rs4[2] = {};
  bf16x8 onesf;
#pragma unroll
  for (int i = 0; i < 8; i++) onesf[i] = (__bf16)1.0f;

  const int rdbase = l4 * 512 + l16 * 8;
  const int vb = 8192 + l4 * 512 + l16 * 8;

  f32x4 sA[2][4], sB[2][4];

#pragma unroll
  for (int i = 0; i < 2; i++) {
    int ic = w * 2 + i;
    gload16(Kh + (size_t)lane * 64 + ic * 8,          sm + ic * 512 + lane * 8);
    gload16(Vh + (size_t)lane * 2048 + ic * 8,        sm + 8192 + ic * 512 + lane * 8);
    gload16(Kh + (size_t)(64 + lane) * 64 + ic * 8,   sm + 4096 + ic * 512 + lane * 8);
    gload16(Vh + (size_t)lane * 2048 + 64 + ic * 8,   sm + 12288 + ic * 512 + lane * 8);
  }
  __syncthreads();

#define QK_N(KLDS, SCUR, n)                                                    \
  {                                                                            \
    bf16x8 kf0 = *(const bf16x8*)((KLDS) + rdbase + (n) * 128);                \
    bf16x8 kf1 = *(const bf16x8*)((KLDS) + rdbase + 2048 + (n) * 128);         \
    f32x4 z = {};                                                              \
    SCUR[0][(n)] = __builtin_amdgcn_mfma_f32_16x16x32_bf16(kf0, qf[0][0], z, 0, 0, 0); \
    SCUR[1][(n)] = __builtin_amdgcn_mfma_f32_16x16x32_bf16(kf0, qf[1][0], z, 0, 0, 0); \
    SCUR[0][(n)] = __builtin_amdgcn_mfma_f32_16x16x32_bf16(kf1, qf[0][1], SCUR[0][(n)], 0, 0, 0); \
    SCUR[1][(n)] = __builtin_amdgcn_mfma_f32_16x16x32_bf16(kf1, qf[1][1], SCUR[1][(n)], 0, 0, 0); \
  }

#define SM_GROUP(SP, st_, g_)                                                  \
  {                                                                            \
    float p0 = exp2_raw(SP[(st_)][2 * (g_)][0]),     p1 = exp2_raw(SP[(st_)][2 * (g_)][1]); \
    float p2 = exp2_raw(SP[(st_)][2 * (g_)][2]),     p3 = exp2_raw(SP[(st_)][2 * (g_)][3]); \
    float p4 = exp2_raw(SP[(st_)][2 * (g_) + 1][0]), p5 = exp2_raw(SP[(st_)][2 * (g_) + 1][1]); \
    float p6 = exp2_raw(SP[(st_)][2 * (g_) + 1][2]), p7 = exp2_raw(SP[(st_)][2 * (g_) + 1][3]); \
    unsigned c00 = cvt_pk_bf16(p0, p1), c01 = cvt_pk_bf16(p2, p3);             \
    unsigned c10 = cvt_pk_bf16(p4, p5), c11 = cvt_pk_bf16(p6, p7);             \
    SWAPL32(c00, c10); SWAPL32(c01, c11);                                      \
    SWAPL16(c00, c10); SWAPL16(c01, c11);                                      \
    u32x4 tv = {c00, c01, c10, c11};                                           \
    pk[(st_)][(g_)] = tv;                                                      \
  }

#define ATTN_ITER(T, CUR, SPREV, SCUR)                                         \
  {                                                                            \
    const __bf16* vlds = sm + (CUR) * 4096;                                    \
    bf16x8 vf[2][4];                                                           \
    _Pragma("unroll")                                                          \
    for (int g = 0; g < 2; g++)                                                \
      _Pragma("unroll")                                                        \
      for (int cb = 0; cb < 4; cb++)                                           \
        vf[g][cb] = *(const bf16x8*)(vlds + vb + g * 2048 + cb * 128);         \
    __syncthreads();                                                           \
    if ((T) + 2 < 32) {                                                        \
      const int kvn = ((T) + 2) * 64;                                          \
      __bf16* dst = sm + (CUR) * 4096;                                         \
      _Pragma("unroll")                                                        \
      for (int i = 0; i < 2; i++) {                                            \
        int ic = w * 2 + i;                                                    \
        gload16(Kh + (size_t)(kvn + lane) * 64 + ic * 8, dst + ic * 512 + lane * 8); \
        gload16(Vh + (size_t)lane * 2048 + kvn + ic * 8, dst + 8192 + ic * 512 + lane * 8); \
      }                                                                        \
    }                                                                          \
    u32x4 pk[2][2];                                                            \
    __builtin_amdgcn_s_setprio(1);                                             \
    if ((T) + 1 < 32) {                                                        \
      const __bf16* klds = sm + ((CUR) ^ 1) * 4096;                            \
      _Pragma("unroll")                                                        \
      for (int n = 0; n < 4; n++) {                                            \
        QK_N(klds, SCUR, n);                                                   \
        SM_GROUP(SPREV, (n >> 1), (n & 1));                                    \
      }                                                                        \
    } else {                                                                   \
      _Pragma("unroll")                                                        \
      for (int n = 0; n < 4; n++) SM_GROUP(SPREV, (n >> 1), (n & 1));          \
    }                                                                          \
    _Pragma("unroll")                                                          \
    for (int st = 0; st < 2; st++)                                             \
      _Pragma("unroll")                                                        \
      for (int g = 0; g < 2; g++) {                                            \
        union { u32x4 u; bf16x8 h; } cv; cv.u = pk[st][g];                     \
        rs4[st] = __builtin_amdgcn_mfma_f32_16x16x32_bf16(onesf, cv.h, rs4[st], 0, 0, 0); \
        _Pragma("unroll")                                                      \
        for (int cb = 0; cb < 4; cb++)                                         \
          ao[st][cb] = __builtin_amdgcn_mfma_f32_16x16x32_bf16(vf[g][cb], cv.h, ao[st][cb], 0, 0, 0); \
      }                                                                        \
    __builtin_amdgcn_s_setprio(0);                                             \
  }

#pragma unroll
  for (int n = 0; n < 4; n++) QK_N(sm, sA, n);

  for (int tkv = 0; tkv < 32; tkv += 2) {
    ATTN_ITER(tkv,     0, sA, sB);
    ATTN_ITER(tkv + 1, 1, sB, sA);
  }
#undef ATTN_ITER
#undef SM_GROUP
#undef QK_N

  const int b_ = bh >> 4, h = bh & 15;
#pragma unroll
  for (int st = 0; st < 2; st++) {
    const float inv = 1.f / rs4[st][0];
    const int qrow = q0 + w * 32 + st * 16 + l16;
#pragma unroll
    for (int cb = 0; cb < 4; cb++) {
      ushort4 ov;
      ov.x = (unsigned short)bf16bits(ao[st][cb][0] * inv);
      ov.y = (unsigned short)bf16bits(ao[st][cb][1] * inv);
      ov.z = (unsigned short)bf16bits(ao[st][cb][2] * inv);
      ov.w = (unsigned short)bf16bits(ao[st][cb][3] * inv);
      *(ushort4*)(O + ((size_t)b_ * 2048 + qrow) * 1024 + h * 64 + cb * 16 + l4 * 4) = ov;
    }
  }
}

// ---------------------------------------------------------------- launch
extern "C" void kernel_launch(void* const* d_in, const int* in_sizes, int n_in,
                              void* d_out, int out_size, void* d_ws, size_t ws_size,
                              hipStream_t stream) {
  const float* x  = (const float*)d_in[0];
  const float* wq = (const float*)d_in[1];
  const float* bq = (const float*)d_in[2];
  const float* wk = (const float*)d_in[3];
  const float* bk = (const float*)d_in[4];
  const float* wv = (const float*)d_in[5];
  const float* bv = (const float*)d_in[6];
  const float* wo = (const float*)d_in[7];
  const float* bo = (const float*)d_in[8];
  float* out = (float*)d_out;

  const size_t NX = 8388608;   // 8192*1024
  const size_t NW = 1048576;   // 1024*1024
  __bf16* xbf = (__bf16*)d_ws;       // also reused as attention output O
  __bf16* wqb = xbf + NX;
  __bf16* wkb = wqb + NW;
  __bf16* wvb = wkb + NW;
  __bf16* wob = wvb + NW;
  __bf16* Qb  = wob + NW;
  __bf16* Kb  = Qb + NX;
  __bf16* Vtb = Kb + NX;

  cast_all<<<6144, 256, 0, stream>>>(x, wq, wk, wv, wo, xbf, wqb, wkb, wvb, wob);

  gemm_qkv<<<dim3(32, 12), 512, 0, stream>>>(xbf, wqb, wkb, wvb, bq, bk, bv,
                                             Qb, Kb, Vtb);
  attn_fwd<<<1024, 256, 0, stream>>>(Qb, Kb, Vtb, xbf /* O */);
  gemm_nt<1><<<dim3(64, 8), 256, 0, stream>>>(xbf, wob, nullptr, nullptr, bo, nullptr, nullptr,
                                              nullptr, nullptr, nullptr, out);
}